// Round 6
// baseline (1930.202 us; speedup 1.0000x reference)
//
#include <hip/hip_runtime.h>
#include <cstdint>
#include <cstddef>

#define RANK_K 819            // kth = sorted[819] (820th smallest of 2048)
// conv: x[64,3,32,32] * w[2048,3,6,6] VALID -> [64,2048,27,27] (never hits HBM)

__device__ __forceinline__ int zbin256(float z) {
  // 256 bins over [-8,8), width 1/16. Monotone partition; selection is exact
  // rank within bin, so binning never affects the kth VALUE.
  float t = (z + 8.0f) * 16.0f;
  t = t < 0.0f ? 0.0f : (t > 255.0f ? 255.0f : t);
  return (int)t;
}

// ------- kernel 1: weight transpose -> wt2[c][kk], kk=(ky*6+kx)*3+ic --------
// Per-thread contiguous k (432 B, 16B-aligned rows -> dwordx4-mergeable).
__global__ __launch_bounds__(256) void net99_wtrans(const float* __restrict__ w,
                                                    float* __restrict__ wt2) {
  int idx = blockIdx.x * 256 + threadIdx.x;
  if (idx < 2048 * 108) {
    int c = idx / 108, kk = idx % 108;
    int ic = kk % 3, sp = kk / 3, ky = sp / 6, kx = sp % 6;
    wt2[idx] = w[c * 108 + ic * 36 + ky * 6 + kx];   // coalesced write
  }
}

// ------- kernel 2: FUSED conv + rank-819 select + mask ----------------------
// block = (y, x-chunk, b). Conv keeps the verified fmaf chain (ky->kx->ic
// ascending per output, f32). Results stay in LDS; select is the proven
// round-5 algorithm reading channels c = tid + 256j from convbuf.
__global__ __launch_bounds__(256) void net99_fused(const float* __restrict__ x,
                                                   const float* __restrict__ wt2,
                                                   const float* __restrict__ bias,
                                                   uint32_t* __restrict__ msk) {
  const int y  = blockIdx.x;        // 0..26
  const int xc = blockIdx.y;        // 0..3 (chunks 7,7,7,6)
  const int b  = blockIdx.z;        // 0..63
  const int x0 = xc * 7;
  const int nq = (xc < 3) ? 7 : 6;
  const int tid  = threadIdx.x;
  const int lane = tid & 63, wid = tid >> 6;

  __shared__ float    xs[3][6][12];        //    864 B  x window (+OOB zeros)
  __shared__ float    convbuf[7][2048];    // 57,344 B  conv rows for 7 pixels
  __shared__ uint32_t hist[2][256];        //  2,048 B
  __shared__ float    cand[2][512];        //  4,096 B
  __shared__ int      cnt[2];
  __shared__ int      sbin[2], sbelow[2];
  __shared__ float    skth[2];

  // stage x window (12 cols starting at x0; col>=32 -> 0, never consumed)
  if (tid < 216) {
    int ic = tid / 72, rem = tid % 72, r = rem / 12, col = rem % 12;
    int gc = x0 + col;
    xs[ic][r][col] = (gc < 32) ? x[((b * 3 + ic) * 32 + (y + r)) * 32 + gc] : 0.0f;
  }
  float biasR[8];
#pragma unroll
  for (int j = 0; j < 8; ++j) biasR[j] = bias[tid + 256 * j];
  __syncthreads();

  // ---- conv phase: 8 channel-tiles x 7 x-positions, chain order preserved --
  float acc[8][7];
#pragma unroll
  for (int ct = 0; ct < 8; ++ct)
#pragma unroll
    for (int q = 0; q < 7; ++q) acc[ct][q] = 0.0f;

  const float* wr = wt2 + (size_t)tid * 108;
  for (int ky = 0; ky < 6; ++ky) {
    float xd[3][12];
#pragma unroll
    for (int i = 0; i < 36; ++i) {
      int ic = i / 12, col = i % 12;
      xd[ic][col] = xs[ic][ky][col];
    }
#pragma unroll
    for (int ct = 0; ct < 8; ++ct) {
      const float* wct = wr + (size_t)ct * (256 * 108) + ky * 18;
#pragma unroll
      for (int kx = 0; kx < 6; ++kx) {
#pragma unroll
        for (int ic = 0; ic < 3; ++ic) {
          float wv = wct[kx * 3 + ic];
#pragma unroll
          for (int q = 0; q < 7; ++q)
            acc[ct][q] = fmaf(wv, xd[ic][kx + q], acc[ct][q]);  // strict chain
        }
      }
    }
  }
#pragma unroll
  for (int ct = 0; ct < 8; ++ct)
#pragma unroll
    for (int q = 0; q < 7; ++q)
      convbuf[q][ct * 256 + tid] = acc[ct][q];
  __syncthreads();

  // ---- select phase: per pixel, exact f32 rank-819 for both branches -------
  for (int q = 0; q < nq; ++q) {
    hist[0][tid] = 0u; hist[1][tid] = 0u;
    if (tid < 2) cnt[tid] = 0;
    float z0[8], z1[8];
#pragma unroll
    for (int j = 0; j < 8; ++j) {
      float v = convbuf[q][tid + 256 * j];
      z0[j] = biasR[j] - v;                 // single f32 op, matches reference
      z1[j] = biasR[j] + v;
    }
    __syncthreads();
#pragma unroll
    for (int j = 0; j < 8; ++j) {
      atomicAdd(&hist[0][zbin256(z0[j])], 1u);
      atomicAdd(&hist[1][zbin256(z1[j])], 1u);
    }
    __syncthreads();
    if (wid < 2) {                          // wave s scans branch s
      const int s = wid;
      int h[4];
#pragma unroll
      for (int t = 0; t < 4; ++t) h[t] = (int)hist[s][lane * 4 + t];
      int loc = h[0] + h[1] + h[2] + h[3];
      int inc = loc;
#pragma unroll
      for (int off = 1; off < 64; off <<= 1) {
        int u = __shfl_up(inc, off);
        if (lane >= off) inc += u;
      }
      int pre = inc - loc;
      if (pre <= RANK_K && RANK_K < pre + loc) {   // exactly one lane
        int cum = pre;
#pragma unroll
        for (int t = 0; t < 4; ++t) {
          if (RANK_K < cum + h[t]) { sbin[s] = lane * 4 + t; sbelow[s] = cum; break; }
          cum += h[t];
        }
      }
    }
    __syncthreads();
    const int tb0 = sbin[0], tb1 = sbin[1];
#pragma unroll
    for (int j = 0; j < 8; ++j) {           // compact target bins from regs
      if (zbin256(z0[j]) == tb0) { int u = atomicAdd(&cnt[0], 1); if (u < 512) cand[0][u] = z0[j]; }
      if (zbin256(z1[j]) == tb1) { int u = atomicAdd(&cnt[1], 1); if (u < 512) cand[1][u] = z1[j]; }
    }
    __syncthreads();
    if (wid < 2) {                          // exact rank, one wave per branch
      const int s = wid;
      int cN = cnt[s] < 512 ? cnt[s] : 512;
      int rloc = RANK_K - sbelow[s];
      for (int ci = lane; ci < cN; ci += 64) {
        float v = cand[s][ci]; int rk = 0;
        for (int j = 0; j < cN; ++j) {
          float u = cand[s][j];
          rk += (u < v) || (u == v && j < ci);
        }
        if (rk == rloc) skth[s] = v;        // unique winning VALUE
      }
    }
    __syncthreads();
    const float km = skth[0], kp = skth[1];
    const int p = y * 27 + x0 + q;
    const size_t base0 = ((size_t)b * 729 + p) * 64;
    const size_t base1 = ((size_t)(64 + b) * 729 + p) * 64;
#pragma unroll
    for (int j = 0; j < 8; ++j) {
      unsigned long long bm = __ballot(z0[j] < km);
      unsigned long long bp = __ballot(z1[j] < kp);
      if (lane == 0 || lane == 32) {
        int wv = 2 * wid + 8 * j + (lane >> 5);
        msk[base0 + wv] = (lane == 0) ? (uint32_t)bm : (uint32_t)(bm >> 32);
        msk[base1 + wv] = (lane == 0) ? (uint32_t)bp : (uint32_t)(bp >> 32);
      }
    }
    // no trailing barrier needed: next pixel's hist/cnt writes are >=3
    // barriers after this pixel's last readers of hist/cand/skth.
  }
}

// ------- kernel 3: bit-exact avg_pool(5,3,ceil) + adaptive(6), LDS-staged ---
__global__ __launch_bounds__(256) void net99_pool(const uint32_t* __restrict__ msk,
                                                  float* __restrict__ out) {
  __shared__ uint32_t stage[729 * 8];   // 23,328 B: full (s,b,cg) mask slice
  const int blk = blockIdx.x;           // 0..1023 = (sb, cg)
  const int cg  = blk & 7;
  const int sb  = blk >> 3;             // s*64 + b
  const int tid = threadIdx.x;
  const uint32_t* src = msk + (size_t)sb * 729 * 64 + cg * 8;
  for (int i = tid; i < 729 * 8; i += 256) {
    int p = i >> 3, w = i & 7;
    stage[i] = src[(size_t)p * 64 + w];
  }
  __syncthreads();
  const int lw = tid >> 5, sel = tid & 31;
  uint32_t rbm[27];
  for (int y = 0; y < 27; ++y) {
    uint32_t rb = 0;
#pragma unroll
    for (int xx = 0; xx < 27; ++xx)
      rb |= ((stage[(y * 27 + xx) * 8 + lw] >> sel) & 1u) << xx;
    rbm[y] = rb;
  }
  constexpr uint32_t WM[9] = {0x1Fu, 0xF8u, 0x7C0u, 0x3E00u, 0x1F000u,
                              0xF8000u, 0x7C0000u, 0x3E00000u, 0x7000000u};
  constexpr int CC[9]  = {5, 5, 5, 5, 5, 5, 5, 5, 3};
  constexpr int BW0[6] = {0, 1, 3, 4, 6, 7};
  constexpr int BW1[6] = {1, 2, 4, 5, 7, 8};
  const int s = sb >> 6, b = sb & 63, c = cg * 256 + tid;
  float* dst = out + (size_t)s * 4718592 + (size_t)(b * 2048 + c) * 36;
  for (int i = 0; i < 6; ++i) {
    float P[2][9];
#pragma unroll
    for (int t = 0; t < 2; ++t) {
      int r  = t ? BW1[i] : BW0[i];
      int y0 = 3 * r;
      int y1 = (y0 + 5 > 27) ? 27 : y0 + 5;
      int cr = y1 - y0;
      int pp[9];
#pragma unroll
      for (int cx = 0; cx < 9; ++cx) pp[cx] = 0;
      for (int yy = y0; yy < y1; ++yy) {
        uint32_t rb = rbm[yy];
#pragma unroll
        for (int cx = 0; cx < 9; ++cx) pp[cx] += __popc(rb & WM[cx]);
      }
#pragma unroll
      for (int cx = 0; cx < 9; ++cx)
        P[t][cx] = (float)pp[cx] / (float)(cr * CC[cx]);   // IEEE f32 div
    }
    float M[9];
#pragma unroll
    for (int cx = 0; cx < 9; ++cx) M[cx] = (P[0][cx] + P[1][cx]) * 0.5f;
#pragma unroll
    for (int j = 0; j < 6; ++j)
      dst[i * 6 + j] = (M[BW0[j]] + M[BW1[j]]) * 0.5f;
  }
}

extern "C" void kernel_launch(void* const* d_in, const int* in_sizes, int n_in,
                              void* d_out, int out_size, void* d_ws, size_t ws_size,
                              hipStream_t stream) {
  const float* x    = (const float*)d_in[0];
  const float* w    = (const float*)d_in[1];
  const float* bias = (const float*)d_in[2];
  float* out = (float*)d_out;
  uint8_t* ws = (uint8_t*)d_ws;

  const size_t WT_BYTES = (size_t)2048 * 108 * 4;          //   884,736
  float*    wt2 = (float*)ws;
  uint32_t* msk = (uint32_t*)(ws + WT_BYTES);              // 23,887,872 B

  hipLaunchKernelGGL(net99_wtrans, dim3((2048 * 108 + 255) / 256), dim3(256), 0, stream, w, wt2);
  hipLaunchKernelGGL(net99_fused, dim3(27, 4, 64), dim3(256), 0, stream, x, wt2, bias, msk);
  hipLaunchKernelGGL(net99_pool, dim3(1024), dim3(256), 0, stream, msk, out);
}

// Round 7
// 493.488 us; speedup vs baseline: 3.9113x; 3.9113x over previous
//
#include <hip/hip_runtime.h>
#include <cstdint>
#include <cstddef>

#define RANK_K 819            // kth = sorted[819] (820th smallest of 2048)
// conv: x[64,3,32,32] * w[2048,3,6,6] VALID -> [64,2048,27,27]

__device__ __forceinline__ int zbin256(float z) {
  // 256 bins over [-8,8), width 1/16. Monotone partition; selection is exact
  // rank within bin, so binning never affects the kth VALUE.
  float t = (z + 8.0f) * 16.0f;
  t = t < 0.0f ? 0.0f : (t > 255.0f ? 255.0f : t);
  return (int)t;
}

// ------- kernel 1: weight transpose w[c][ic][ky][kx] -> wt[(ky,kx,ic)][c] ---
__global__ __launch_bounds__(256) void net99_wtrans(const float* __restrict__ w,
                                                    float* __restrict__ wt) {
  int idx = blockIdx.x * 256 + threadIdx.x;
  if (idx < 2048 * 108) {
    int kk = idx / 2048, c = idx % 2048;
    int ic = kk % 3, sp = kk / 3, ky = sp / 6, kx = sp % 6;
    wt[idx] = w[c * 108 + ic * 36 + ky * 6 + kx];   // coalesced write
  }
}

// ------- kernel 2: f32 conv, sequential-FMA in (ky,kx,ic) order -------------
// UNCHANGED (proven 86% VALUBusy, bit-exact chain order). Do not touch.
__global__ __launch_bounds__(256) void net99_conv(const float* __restrict__ x,
                                                  const float* __restrict__ wt,
                                                  float* __restrict__ conv, int b0) {
  const int y  = blockIdx.x;       // 0..26
  const int ct = blockIdx.y;       // 0..7 (channel tile of 256)
  const int bl = blockIdx.z;       // local batch
  const int b  = b0 + bl;
  const int tid = threadIdx.x;
  __shared__ float xs[3][6][32];
  for (int i = tid; i < 576; i += 256) {
    int ic = i / 192, rem = i % 192, r = rem / 32, col = rem % 32;
    xs[ic][r][col] = x[((b * 3 + ic) * 32 + (y + r)) * 32 + col];
  }
  __syncthreads();
  const int c = ct * 256 + tid;
  const float* wtc = wt + c;
  float acc[27];
#pragma unroll
  for (int q = 0; q < 27; ++q) acc[q] = 0.0f;
  for (int ky = 0; ky < 6; ++ky) {   // NOT unrolled: bounds register pressure
    float xd[3][32];
#pragma unroll
    for (int i = 0; i < 96; ++i) {   // contiguous -> ds_read_b128 bursts
      int ic = i >> 5, col = i & 31;
      xd[ic][col] = xs[ic][ky][col];
    }
#pragma unroll
    for (int kx = 0; kx < 6; ++kx) {
#pragma unroll
      for (int ic = 0; ic < 3; ++ic) {
        float wv = wtc[(size_t)((ky * 6 + kx) * 3 + ic) * 2048];
#pragma unroll
        for (int q = 0; q < 27; ++q)
          acc[q] = fmaf(wv, xd[ic][kx + q], acc[q]);   // strict chain order
      }
    }
  }
  float* dst = conv + ((size_t)(bl * 27 + y) * 27) * 2048 + c;
#pragma unroll
  for (int q = 0; q < 27; ++q) dst[(size_t)q * 2048] = acc[q];
}

// ------- kernel 3: 2-pixel register-resident rank-819 select + byte mask ----
// Block handles pixels p0=2g, p1=2g+1 -> 4 streams (pixel x branch). Wave w
// owns stream w in scan+rank (all 4 waves busy). Thread t owns channels
// 8t..8t+7; z-values live in VGPRs end-to-end. 6 barriers per 2 pixels.
__global__ __launch_bounds__(256) void net99_select(const float* __restrict__ conv,
                                                    const float* __restrict__ bias,
                                                    uint8_t* __restrict__ mskb, int b0) {
  const int bl = blockIdx.x / 365;
  const int g  = blockIdx.x % 365;
  const int p0 = 2 * g;
  const bool has1 = (p0 + 1) < 729;
  const int gb = b0 + bl;
  const int tid  = threadIdx.x;
  const int lane = tid & 63;
  const int wid  = tid >> 6;
  const int nst  = has1 ? 4 : 2;
  __shared__ uint32_t hist[4][256];
  __shared__ float    cand[4][512];
  __shared__ int      cnt[4];
  __shared__ int      sbin[4], sbelow[4];
  __shared__ float    skth[4];

  // issue all global loads first (hide latency under LDS init + z math)
  const float4* __restrict__ s0 =
      (const float4*)(conv + ((size_t)bl * 729 + p0) * 2048) + tid * 2;
  const float4* __restrict__ b4 = (const float4*)bias + tid * 2;
  float4 va0 = s0[0], vb0 = s0[1];
  float4 va1 = {}, vb1 = {};
  if (has1) { va1 = s0[512]; vb1 = s0[513]; }     // +2048 floats = +512 float4
  float4 ba = b4[0], bb = b4[1];

  (&hist[0][0])[tid]       = 0u;
  (&hist[0][0])[tid + 256] = 0u;
  (&hist[0][0])[tid + 512] = 0u;
  (&hist[0][0])[tid + 768] = 0u;
  if (tid < 4) cnt[tid] = 0;

  float z[4][8];
  {
    float bv[8] = {ba.x, ba.y, ba.z, ba.w, bb.x, bb.y, bb.z, bb.w};
    float v0[8] = {va0.x, va0.y, va0.z, va0.w, vb0.x, vb0.y, vb0.z, vb0.w};
    float v1[8] = {va1.x, va1.y, va1.z, va1.w, vb1.x, vb1.y, vb1.z, vb1.w};
#pragma unroll
    for (int j = 0; j < 8; ++j) {
      z[0][j] = bv[j] - v0[j];   // single f32 op each, matches reference
      z[1][j] = bv[j] + v0[j];
      z[2][j] = bv[j] - v1[j];
      z[3][j] = bv[j] + v1[j];
    }
  }
  __syncthreads();                                  // hist zeros visible
#pragma unroll
  for (int j = 0; j < 8; ++j) {
    atomicAdd(&hist[0][zbin256(z[0][j])], 1u);
    atomicAdd(&hist[1][zbin256(z[1][j])], 1u);
  }
  if (has1) {
#pragma unroll
    for (int j = 0; j < 8; ++j) {
      atomicAdd(&hist[2][zbin256(z[2][j])], 1u);
      atomicAdd(&hist[3][zbin256(z[3][j])], 1u);
    }
  }
  __syncthreads();
  if (wid < nst) {                      // wave w scans stream w (no barriers)
    const int s = wid;
    int h[4];
#pragma unroll
    for (int t = 0; t < 4; ++t) h[t] = (int)hist[s][lane * 4 + t];
    int loc = h[0] + h[1] + h[2] + h[3];
    int inc = loc;
#pragma unroll
    for (int off = 1; off < 64; off <<= 1) {
      int u = __shfl_up(inc, off);
      if (lane >= off) inc += u;
    }
    int pre = inc - loc;
    if (pre <= RANK_K && RANK_K < pre + loc) {      // exactly one lane
      int cum = pre;
#pragma unroll
      for (int t = 0; t < 4; ++t) {
        if (RANK_K < cum + h[t]) { sbin[s] = lane * 4 + t; sbelow[s] = cum; break; }
        cum += h[t];
      }
    }
  }
  __syncthreads();
#pragma unroll
  for (int s = 0; s < 4; ++s) {                     // compact from registers
    if (s >= 2 && !has1) break;
    const int tb = sbin[s];
#pragma unroll
    for (int j = 0; j < 8; ++j) {
      if (zbin256(z[s][j]) == tb) {
        int u = atomicAdd(&cnt[s], 1);
        if (u < 512) cand[s][u] = z[s][j];
      }
    }
  }
  __syncthreads();
  if (wid < nst) {                      // exact rank, one wave per stream
    const int s = wid;
    int cN = cnt[s] < 512 ? cnt[s] : 512;
    int rloc = RANK_K - sbelow[s];
    for (int ci = lane; ci < cN; ci += 64) {
      float v = cand[s][ci]; int rk = 0;
      for (int j = 0; j < cN; ++j) {
        float u = cand[s][j];
        rk += (u < v) || (u == v && j < ci);
      }
      if (rk == rloc) skth[s] = v;                  // unique winning VALUE
    }
  }
  __syncthreads();
  const size_t pix0 = (size_t)gb * 729 + p0;
  {
    uint32_t m0 = 0u, m1 = 0u;
    const float k0 = skth[0], k1 = skth[1];
#pragma unroll
    for (int j = 0; j < 8; ++j) {
      m0 |= (uint32_t)(z[0][j] < k0) << j;
      m1 |= (uint32_t)(z[1][j] < k1) << j;
    }
    mskb[pix0 * 256 + tid]                        = (uint8_t)m0;
    mskb[((size_t)64 * 729 + pix0) * 256 + tid]   = (uint8_t)m1;
  }
  if (has1) {
    uint32_t m2 = 0u, m3 = 0u;
    const float k2 = skth[2], k3 = skth[3];
#pragma unroll
    for (int j = 0; j < 8; ++j) {
      m2 |= (uint32_t)(z[2][j] < k2) << j;
      m3 |= (uint32_t)(z[3][j] < k3) << j;
    }
    mskb[(pix0 + 1) * 256 + tid]                      = (uint8_t)m2;
    mskb[((size_t)64 * 729 + pix0 + 1) * 256 + tid]   = (uint8_t)m3;
  }
}

// ------- kernel 4: bit-exact avg_pool(5,3,ceil) + adaptive(6), LDS-staged ---
__global__ __launch_bounds__(256) void net99_pool(const uint32_t* __restrict__ msk,
                                                  float* __restrict__ out) {
  __shared__ uint32_t stage[729 * 8];   // 23,328 B: full (s,b,cg) mask slice
  const int blk = blockIdx.x;           // 0..1023 = (sb, cg)
  const int cg  = blk & 7;
  const int sb  = blk >> 3;             // s*64 + b
  const int tid = threadIdx.x;
  const uint32_t* src = msk + (size_t)sb * 729 * 64 + cg * 8;
  for (int i = tid; i < 729 * 8; i += 256) {
    int p = i >> 3, w = i & 7;
    stage[i] = src[(size_t)p * 64 + w];
  }
  __syncthreads();
  const int lw = tid >> 5, sel = tid & 31;
  uint32_t rbm[27];
  for (int y = 0; y < 27; ++y) {
    uint32_t rb = 0;
#pragma unroll
    for (int xx = 0; xx < 27; ++xx)
      rb |= ((stage[(y * 27 + xx) * 8 + lw] >> sel) & 1u) << xx;
    rbm[y] = rb;
  }
  constexpr uint32_t WM[9] = {0x1Fu, 0xF8u, 0x7C0u, 0x3E00u, 0x1F000u,
                              0xF8000u, 0x7C0000u, 0x3E00000u, 0x7000000u};
  constexpr int CC[9]  = {5, 5, 5, 5, 5, 5, 5, 5, 3};
  constexpr int BW0[6] = {0, 1, 3, 4, 6, 7};
  constexpr int BW1[6] = {1, 2, 4, 5, 7, 8};
  const int s = sb >> 6, b = sb & 63, c = cg * 256 + tid;
  float* dst = out + (size_t)s * 4718592 + (size_t)(b * 2048 + c) * 36;
  for (int i = 0; i < 6; ++i) {
    float P[2][9];
#pragma unroll
    for (int t = 0; t < 2; ++t) {
      int r  = t ? BW1[i] : BW0[i];
      int y0 = 3 * r;
      int y1 = (y0 + 5 > 27) ? 27 : y0 + 5;
      int cr = y1 - y0;
      int pp[9];
#pragma unroll
      for (int cx = 0; cx < 9; ++cx) pp[cx] = 0;
      for (int yy = y0; yy < y1; ++yy) {
        uint32_t rb = rbm[yy];
#pragma unroll
        for (int cx = 0; cx < 9; ++cx) pp[cx] += __popc(rb & WM[cx]);
      }
#pragma unroll
      for (int cx = 0; cx < 9; ++cx)
        P[t][cx] = (float)pp[cx] / (float)(cr * CC[cx]);   // IEEE f32 div
    }
    float M[9];
#pragma unroll
    for (int cx = 0; cx < 9; ++cx) M[cx] = (P[0][cx] + P[1][cx]) * 0.5f;
#pragma unroll
    for (int j = 0; j < 6; ++j)
      dst[i * 6 + j] = (M[BW0[j]] + M[BW1[j]]) * 0.5f;
  }
}

extern "C" void kernel_launch(void* const* d_in, const int* in_sizes, int n_in,
                              void* d_out, int out_size, void* d_ws, size_t ws_size,
                              hipStream_t stream) {
  const float* x    = (const float*)d_in[0];
  const float* w    = (const float*)d_in[1];
  const float* bias = (const float*)d_in[2];
  float* out = (float*)d_out;
  uint8_t* ws = (uint8_t*)d_ws;

  const size_t WT_BYTES   = (size_t)108 * 2048 * 4;          //   884,736
  const size_t MASK_OFF   = WT_BYTES;
  const size_t MASK_BYTES = (size_t)2 * 64 * 729 * 64 * 4;   // 23,887,872
  const size_t CONV_OFF   = MASK_OFF + MASK_BYTES;           // 24,772,608
  const size_t PER_B      = (size_t)2048 * 729 * 4;          // 5,971,968 per batch

  float*    wt   = (float*)ws;
  uint8_t*  mskb = (uint8_t*)(ws + MASK_OFF);
  uint32_t* msk  = (uint32_t*)(ws + MASK_OFF);
  float*    conv = (float*)(ws + CONV_OFF);

  size_t avail = ws_size > CONV_OFF ? ws_size - CONV_OFF : 0;
  int Bc = (int)(avail / PER_B);
  if (Bc < 1) Bc = 1;       // assumes ws_size >= ~31 MB
  if (Bc > 64) Bc = 64;

  hipLaunchKernelGGL(net99_wtrans, dim3((2048 * 108 + 255) / 256), dim3(256), 0, stream, w, wt);
  for (int b0 = 0; b0 < 64; b0 += Bc) {
    int nb = (64 - b0 < Bc) ? (64 - b0) : Bc;
    hipLaunchKernelGGL(net99_conv, dim3(27, 8, nb), dim3(256), 0, stream, x, wt, conv, b0);
    hipLaunchKernelGGL(net99_select, dim3(nb * 365), dim3(256), 0, stream, conv, bias, mskb, b0);
  }
  hipLaunchKernelGGL(net99_pool, dim3(1024), dim3(256), 0, stream, msk, out);
}

// Round 8
// 476.230 us; speedup vs baseline: 4.0531x; 1.0362x over previous
//
#include <hip/hip_runtime.h>
#include <cstdint>
#include <cstddef>

#define RANK_K 819            // kth = sorted[819] (820th smallest of 2048)
// conv: x[64,3,32,32] * w[2048,3,6,6] VALID -> [64,2048,27,27]

typedef __attribute__((ext_vector_type(2))) float f32x2;

// packed f32 FMA: two independent IEEE fma ops (lo,hi) in one instruction.
// Each half is a separate single-rounding fma -> per-output chain unchanged.
__device__ __forceinline__ f32x2 pk_fma(f32x2 a, f32x2 b, f32x2 c) {
  f32x2 d;
  asm("v_pk_fma_f32 %0, %1, %2, %3" : "=v"(d) : "v"(a), "v"(b), "v"(c));
  return d;
}

__device__ __forceinline__ int zbin256(float z) {
  // 256 bins over [-8,8), width 1/16. Monotone partition; selection is exact
  // rank within bin, so binning never affects the kth VALUE.
  float t = (z + 8.0f) * 16.0f;
  t = t < 0.0f ? 0.0f : (t > 255.0f ? 255.0f : t);
  return (int)t;
}

// ------- kernel 1: weight transpose w[c][ic][ky][kx] -> wt[(ky,kx,ic)][c] ---
__global__ __launch_bounds__(256) void net99_wtrans(const float* __restrict__ w,
                                                    float* __restrict__ wt) {
  int idx = blockIdx.x * 256 + threadIdx.x;
  if (idx < 2048 * 108) {
    int kk = idx / 2048, c = idx % 2048;
    int ic = kk % 3, sp = kk / 3, ky = sp / 6, kx = sp % 6;
    wt[idx] = w[c * 108 + ic * 36 + ky * 6 + kx];   // coalesced write
  }
}

// ------- kernel 2: f32 conv via v_pk_fma_f32, chain order (ky,kx,ic) --------
// Outputs paired (q, q+13); pair array xs2[m] = (row[m], row[m+13]) so each
// pk_fma B-operand is one aligned VGPR pair. Output 26 = scalar chain reading
// hi half of pair kx+13 (= row[kx+26]). Bit-exact vs the proven kernel.
__global__ __launch_bounds__(256, 2) void net99_conv(const float* __restrict__ x,
                                                     const float* __restrict__ wt,
                                                     float* __restrict__ conv, int b0) {
  const int y  = blockIdx.x;       // 0..26
  const int ct = blockIdx.y;       // 0..7 (channel tile of 256)
  const int bl = blockIdx.z;       // local batch
  const int b  = b0 + bl;
  const int tid = threadIdx.x;
  __shared__ float xs[3][6][32];
  __shared__ f32x2 xs2[3][6][19];  // pair m = (row[m], row[m+13]), m=0..18
  for (int i = tid; i < 576; i += 256) {
    int ic = i / 192, rem = i % 192, r = rem / 32, col = rem % 32;
    xs[ic][r][col] = x[((b * 3 + ic) * 32 + (y + r)) * 32 + col];
  }
  __syncthreads();
  for (int i = tid; i < 342; i += 256) {
    int ic = i / 114, rem = i % 114, r = rem / 19, m = rem % 19;
    f32x2 t; t.x = xs[ic][r][m]; t.y = xs[ic][r][m + 13];
    xs2[ic][r][m] = t;
  }
  __syncthreads();
  const int c = ct * 256 + tid;
  const float* wtc = wt + c;
  f32x2 acc2[13];
  float acc26 = 0.0f;
#pragma unroll
  for (int j = 0; j < 13; ++j) acc2[j] = (f32x2)(0.0f);
#pragma unroll 1
  for (int ky = 0; ky < 6; ++ky) {   // runtime loop: bounds register pressure
    f32x2 xp[3][19];
#pragma unroll
    for (int ic = 0; ic < 3; ++ic)
#pragma unroll
      for (int m = 0; m < 19; ++m) xp[ic][m] = xs2[ic][ky][m];
#pragma unroll
    for (int kx = 0; kx < 6; ++kx) {
#pragma unroll
      for (int ic = 0; ic < 3; ++ic) {
        float wv = wtc[(size_t)((ky * 6 + kx) * 3 + ic) * 2048];
        f32x2 wvv; wvv.x = wv; wvv.y = wv;
#pragma unroll
        for (int j = 0; j < 13; ++j)
          acc2[j] = pk_fma(wvv, xp[ic][kx + j], acc2[j]);   // outputs j, j+13
        acc26 = fmaf(wv, xp[ic][kx + 13].y, acc26);          // output 26
      }
    }
  }
  float* dst = conv + ((size_t)(bl * 27 + y) * 27) * 2048 + c;
#pragma unroll
  for (int j = 0; j < 13; ++j) {
    dst[(size_t)j * 2048]        = acc2[j].x;
    dst[(size_t)(j + 13) * 2048] = acc2[j].y;
  }
  dst[(size_t)26 * 2048] = acc26;
}

// ------- kernel 3: 2-pixel register-resident rank-819 select + byte mask ----
// UNCHANGED from round 7 (passing, bit-exact).
__global__ __launch_bounds__(256) void net99_select(const float* __restrict__ conv,
                                                    const float* __restrict__ bias,
                                                    uint8_t* __restrict__ mskb, int b0) {
  const int bl = blockIdx.x / 365;
  const int g  = blockIdx.x % 365;
  const int p0 = 2 * g;
  const bool has1 = (p0 + 1) < 729;
  const int gb = b0 + bl;
  const int tid  = threadIdx.x;
  const int lane = tid & 63;
  const int wid  = tid >> 6;
  const int nst  = has1 ? 4 : 2;
  __shared__ uint32_t hist[4][256];
  __shared__ float    cand[4][512];
  __shared__ int      cnt[4];
  __shared__ int      sbin[4], sbelow[4];
  __shared__ float    skth[4];

  const float4* __restrict__ s0 =
      (const float4*)(conv + ((size_t)bl * 729 + p0) * 2048) + tid * 2;
  const float4* __restrict__ b4 = (const float4*)bias + tid * 2;
  float4 va0 = s0[0], vb0 = s0[1];
  float4 va1 = {}, vb1 = {};
  if (has1) { va1 = s0[512]; vb1 = s0[513]; }
  float4 ba = b4[0], bb = b4[1];

  (&hist[0][0])[tid]       = 0u;
  (&hist[0][0])[tid + 256] = 0u;
  (&hist[0][0])[tid + 512] = 0u;
  (&hist[0][0])[tid + 768] = 0u;
  if (tid < 4) cnt[tid] = 0;

  float z[4][8];
  {
    float bv[8] = {ba.x, ba.y, ba.z, ba.w, bb.x, bb.y, bb.z, bb.w};
    float v0[8] = {va0.x, va0.y, va0.z, va0.w, vb0.x, vb0.y, vb0.z, vb0.w};
    float v1[8] = {va1.x, va1.y, va1.z, va1.w, vb1.x, vb1.y, vb1.z, vb1.w};
#pragma unroll
    for (int j = 0; j < 8; ++j) {
      z[0][j] = bv[j] - v0[j];
      z[1][j] = bv[j] + v0[j];
      z[2][j] = bv[j] - v1[j];
      z[3][j] = bv[j] + v1[j];
    }
  }
  __syncthreads();
#pragma unroll
  for (int j = 0; j < 8; ++j) {
    atomicAdd(&hist[0][zbin256(z[0][j])], 1u);
    atomicAdd(&hist[1][zbin256(z[1][j])], 1u);
  }
  if (has1) {
#pragma unroll
    for (int j = 0; j < 8; ++j) {
      atomicAdd(&hist[2][zbin256(z[2][j])], 1u);
      atomicAdd(&hist[3][zbin256(z[3][j])], 1u);
    }
  }
  __syncthreads();
  if (wid < nst) {
    const int s = wid;
    int h[4];
#pragma unroll
    for (int t = 0; t < 4; ++t) h[t] = (int)hist[s][lane * 4 + t];
    int loc = h[0] + h[1] + h[2] + h[3];
    int inc = loc;
#pragma unroll
    for (int off = 1; off < 64; off <<= 1) {
      int u = __shfl_up(inc, off);
      if (lane >= off) inc += u;
    }
    int pre = inc - loc;
    if (pre <= RANK_K && RANK_K < pre + loc) {
      int cum = pre;
#pragma unroll
      for (int t = 0; t < 4; ++t) {
        if (RANK_K < cum + h[t]) { sbin[s] = lane * 4 + t; sbelow[s] = cum; break; }
        cum += h[t];
      }
    }
  }
  __syncthreads();
#pragma unroll
  for (int s = 0; s < 4; ++s) {
    if (s >= 2 && !has1) break;
    const int tb = sbin[s];
#pragma unroll
    for (int j = 0; j < 8; ++j) {
      if (zbin256(z[s][j]) == tb) {
        int u = atomicAdd(&cnt[s], 1);
        if (u < 512) cand[s][u] = z[s][j];
      }
    }
  }
  __syncthreads();
  if (wid < nst) {
    const int s = wid;
    int cN = cnt[s] < 512 ? cnt[s] : 512;
    int rloc = RANK_K - sbelow[s];
    for (int ci = lane; ci < cN; ci += 64) {
      float v = cand[s][ci]; int rk = 0;
      for (int j = 0; j < cN; ++j) {
        float u = cand[s][j];
        rk += (u < v) || (u == v && j < ci);
      }
      if (rk == rloc) skth[s] = v;
    }
  }
  __syncthreads();
  const size_t pix0 = (size_t)gb * 729 + p0;
  {
    uint32_t m0 = 0u, m1 = 0u;
    const float k0 = skth[0], k1 = skth[1];
#pragma unroll
    for (int j = 0; j < 8; ++j) {
      m0 |= (uint32_t)(z[0][j] < k0) << j;
      m1 |= (uint32_t)(z[1][j] < k1) << j;
    }
    mskb[pix0 * 256 + tid]                      = (uint8_t)m0;
    mskb[((size_t)64 * 729 + pix0) * 256 + tid] = (uint8_t)m1;
  }
  if (has1) {
    uint32_t m2 = 0u, m3 = 0u;
    const float k2 = skth[2], k3 = skth[3];
#pragma unroll
    for (int j = 0; j < 8; ++j) {
      m2 |= (uint32_t)(z[2][j] < k2) << j;
      m3 |= (uint32_t)(z[3][j] < k3) << j;
    }
    mskb[(pix0 + 1) * 256 + tid]                      = (uint8_t)m2;
    mskb[((size_t)64 * 729 + pix0 + 1) * 256 + tid]   = (uint8_t)m3;
  }
}

// ------- kernel 4: bit-exact avg_pool(5,3,ceil) + adaptive(6), LDS-staged ---
__global__ __launch_bounds__(256) void net99_pool(const uint32_t* __restrict__ msk,
                                                  float* __restrict__ out) {
  __shared__ uint32_t stage[729 * 8];   // 23,328 B: full (s,b,cg) mask slice
  const int blk = blockIdx.x;           // 0..1023 = (sb, cg)
  const int cg  = blk & 7;
  const int sb  = blk >> 3;             // s*64 + b
  const int tid = threadIdx.x;
  const uint32_t* src = msk + (size_t)sb * 729 * 64 + cg * 8;
  for (int i = tid; i < 729 * 8; i += 256) {
    int p = i >> 3, w = i & 7;
    stage[i] = src[(size_t)p * 64 + w];
  }
  __syncthreads();
  const int lw = tid >> 5, sel = tid & 31;
  uint32_t rbm[27];
  for (int y = 0; y < 27; ++y) {
    uint32_t rb = 0;
#pragma unroll
    for (int xx = 0; xx < 27; ++xx)
      rb |= ((stage[(y * 27 + xx) * 8 + lw] >> sel) & 1u) << xx;
    rbm[y] = rb;
  }
  constexpr uint32_t WM[9] = {0x1Fu, 0xF8u, 0x7C0u, 0x3E00u, 0x1F000u,
                              0xF8000u, 0x7C0000u, 0x3E00000u, 0x7000000u};
  constexpr int CC[9]  = {5, 5, 5, 5, 5, 5, 5, 5, 3};
  constexpr int BW0[6] = {0, 1, 3, 4, 6, 7};
  constexpr int BW1[6] = {1, 2, 4, 5, 7, 8};
  const int s = sb >> 6, b = sb & 63, c = cg * 256 + tid;
  float* dst = out + (size_t)s * 4718592 + (size_t)(b * 2048 + c) * 36;
  for (int i = 0; i < 6; ++i) {
    float P[2][9];
#pragma unroll
    for (int t = 0; t < 2; ++t) {
      int r  = t ? BW1[i] : BW0[i];
      int y0 = 3 * r;
      int y1 = (y0 + 5 > 27) ? 27 : y0 + 5;
      int cr = y1 - y0;
      int pp[9];
#pragma unroll
      for (int cx = 0; cx < 9; ++cx) pp[cx] = 0;
      for (int yy = y0; yy < y1; ++yy) {
        uint32_t rb = rbm[yy];
#pragma unroll
        for (int cx = 0; cx < 9; ++cx) pp[cx] += __popc(rb & WM[cx]);
      }
#pragma unroll
      for (int cx = 0; cx < 9; ++cx)
        P[t][cx] = (float)pp[cx] / (float)(cr * CC[cx]);   // IEEE f32 div
    }
    float M[9];
#pragma unroll
    for (int cx = 0; cx < 9; ++cx) M[cx] = (P[0][cx] + P[1][cx]) * 0.5f;
#pragma unroll
    for (int j = 0; j < 6; ++j)
      dst[i * 6 + j] = (M[BW0[j]] + M[BW1[j]]) * 0.5f;
  }
}

extern "C" void kernel_launch(void* const* d_in, const int* in_sizes, int n_in,
                              void* d_out, int out_size, void* d_ws, size_t ws_size,
                              hipStream_t stream) {
  const float* x    = (const float*)d_in[0];
  const float* w    = (const float*)d_in[1];
  const float* bias = (const float*)d_in[2];
  float* out = (float*)d_out;
  uint8_t* ws = (uint8_t*)d_ws;

  const size_t WT_BYTES   = (size_t)108 * 2048 * 4;          //   884,736
  const size_t MASK_OFF   = WT_BYTES;
  const size_t MASK_BYTES = (size_t)2 * 64 * 729 * 64 * 4;   // 23,887,872
  const size_t CONV_OFF   = MASK_OFF + MASK_BYTES;           // 24,772,608
  const size_t PER_B      = (size_t)2048 * 729 * 4;          // 5,971,968 per batch

  float*    wt   = (float*)ws;
  uint8_t*  mskb = (uint8_t*)(ws + MASK_OFF);
  uint32_t* msk  = (uint32_t*)(ws + MASK_OFF);
  float*    conv = (float*)(ws + CONV_OFF);

  size_t avail = ws_size > CONV_OFF ? ws_size - CONV_OFF : 0;
  int Bc = (int)(avail / PER_B);
  if (Bc < 1) Bc = 1;       // assumes ws_size >= ~31 MB
  if (Bc > 64) Bc = 64;

  hipLaunchKernelGGL(net99_wtrans, dim3((2048 * 108 + 255) / 256), dim3(256), 0, stream, w, wt);
  for (int b0 = 0; b0 < 64; b0 += Bc) {
    int nb = (64 - b0 < Bc) ? (64 - b0) : Bc;
    hipLaunchKernelGGL(net99_conv, dim3(27, 8, nb), dim3(256), 0, stream, x, wt, conv, b0);
    hipLaunchKernelGGL(net99_select, dim3(nb * 365), dim3(256), 0, stream, conv, bias, mskb, b0);
  }
  hipLaunchKernelGGL(net99_pool, dim3(1024), dim3(256), 0, stream, msk, out);
}